// Round 9
// baseline (126.843 us; speedup 1.0000x reference)
//
#include <hip/hip_runtime.h>

// Problem: b=4, c=64, h=w=128, ks=3, N=9, offset ch=18, oc=64. Padded HP=130.
#define BATCH 4
#define CH    64
#define HH    128
#define WW    128
#define HW    (HH*WW)
#define HP    130
#define NOFF  18
#define OC    64

typedef _Float16 half8 __attribute__((ext_vector_type(8)));
typedef float f32x4 __attribute__((ext_vector_type(4)));

// ws layout (bytes):
//   wf  @ 0      : 36864 f16 (main A-frags)    pf @ 73728: 18432 f16
//   x0t @ 110592 : 4*130*130*64 f16 (padded NHWC, zero ring)
//   x1t @ 8763392: same                        total 17416192 B
#define WF_OFF  0
#define PF_OFF  73728
#define X0T_OFF 110592
#define X1T_OFF 8763392

// ---------------------------------------------------------------------------
// Kernel A: blocks 0..2047 transpose half-rows NCHW f32 -> padded NHWC f16;
// 2048..2063 zero ring rows; 2064..2279 A-fragments (k-major t = k*64+c).
// ---------------------------------------------------------------------------
__global__ __launch_bounds__(256) void prep_all(
    const float* __restrict__ x0, const float* __restrict__ x1,
    const float* __restrict__ cw, const float* __restrict__ pw,
    _Float16* __restrict__ x0t, _Float16* __restrict__ x1t,
    _Float16* __restrict__ wf, _Float16* __restrict__ pf) {
  int blk = blockIdx.x, tid = threadIdx.x;
  if (blk < 2048) {
    __shared__ float tile[64 * 66];
    int jh = blk & 1, i = (blk >> 1) & 127, b = (blk >> 8) & 3, which = blk >> 10;
    const float* src = which ? x1 : x0;
    _Float16* dst = which ? x1t : x0t;
#pragma unroll
    for (int it = 0; it < 4; it++) {
      int idx = it * 256 + tid;            // 1024 float4 = 64c x 64j
      int c = idx >> 4, j4 = (idx & 15) << 2;
      float4 v = *(const float4*)(src + (size_t)(b * CH + c) * HW + i * WW + jh * 64 + j4);
      *(float4*)&tile[c * 66 + j4] = v;
    }
    __syncthreads();
    int jl = tid >> 2, cq = (tid & 3) << 4;
    _Float16* dp = dst + ((size_t)(b * HP + i + 1) * HP + (jh * 64 + jl + 1)) * CH + cq;
#pragma unroll
    for (int h = 0; h < 2; h++) {
      half8 v;
#pragma unroll
      for (int cc = 0; cc < 8; cc++) v[cc] = (_Float16)tile[(cq + h * 8 + cc) * 66 + jl];
      *(half8*)(dp + h * 8) = v;
    }
    if (tid < 8) {                          // ring column jo=0 (jh0) / jo=129 (jh1)
      int jo = jh ? (HP - 1) : 0;
      _Float16* zp = dst + ((size_t)(b * HP + i + 1) * HP + jo) * CH + tid * 8;
      int4 z = {0, 0, 0, 0};
      *(int4*)zp = z;
    }
  } else if (blk < 2064) {
    int z = blk - 2048;
    int which = z >> 3, b = (z >> 1) & 3, top = z & 1;
    _Float16* dst = (which ? x1t : x0t) + ((size_t)(b * HP + top * (HP - 1)) * HP) * CH;
    int4 zz = {0, 0, 0, 0};
    for (int e = tid; e < 1040; e += 256) *(int4*)((char*)dst + e * 16) = zz;
  } else {
    int gid = (blk - 2064) * 256 + tid;     // 216*256 = 36864 + 18432
    if (gid < 36864) {
      int j = gid & 7, lane = (gid >> 3) & 63, mt = (gid >> 9) & 3, s = gid >> 11;
      int oc = mt * 16 + (lane & 15);
      int t = s * 32 + (lane >> 4) * 8 + j;
      int k = t >> 6, c = t & 63;
      wf[gid] = (_Float16)cw[(oc * CH + c) * 9 + k];
    } else {
      int g = gid - 36864;
      int j = g & 7, lane = (g >> 3) & 63, mt = (g >> 9) & 1, s = g >> 10;
      int o = mt * 16 + (lane & 15);
      int t = s * 32 + (lane >> 4) * 8 + j;
      int k = t >> 6, c = t & 63;
      pf[g] = (o < NOFF) ? (_Float16)pw[(o * CH + c) * 9 + k] : (_Float16)0.f;
    }
  }
}

// ---------------------------------------------------------------------------
// Kernel B: fully fused. Block = 32-px strip (b, i, j0), 256 thr, 4 blocks/CU
// (LDS 39424 B). Phases:
//  1. offset GEMM: D[o][px], M=32 (18 used), K=576; B-frags straight from
//     x1t (block's 3x34-px patch ~13 KB, L1-resident) -> offs LDS.
//  2. gather: tid = px*8+cg; interp weights computed inline from offs
//     (broadcast LDS read, redundant x8 lanes - VALU is idle); 4 coalesced
//     corner loads; in-lane interp -> half8 IS one B-frag slot ->
//     ds_write_b128 into frag-ordered btile.
//  3. main GEMM: D[oc][px], M=64, K=576, lane-indexed ds_read_b128 + MFMA.
// XCD band swizzle: each XCD owns 64 contiguous rows of one image.
// ---------------------------------------------------------------------------
__global__ __launch_bounds__(256, 4) void deform_all(
    const _Float16* __restrict__ x0t, const _Float16* __restrict__ x1t,
    const _Float16* __restrict__ pf, const float* __restrict__ pb,
    const _Float16* __restrict__ wf, float* __restrict__ out) {
  __shared__ __align__(16) _Float16 btile[2 * 18 * 64 * 8];   // 36864 B
  __shared__ float offs[32 * 20];                             // 2560 B

  int xcd = blockIdx.x & 7, local = blockIdx.x >> 3;
  int strip = xcd * 256 + local;            // 0..2047
  int jq2 = strip & 3, i = (strip >> 2) & 127, b = strip >> 9;
  int j0 = jq2 * 32;
  int tid = threadIdx.x;
  const _Float16* x0b = x0t + (size_t)b * HP * HP * CH;
  const _Float16* x1b = x1t + (size_t)b * HP * HP * CH;

  // ---- Phase 1: offset GEMM (M=32 padded from 18, K=576) ----
  {
    int lane = tid & 63, w = tid >> 6;
    int nt = w & 1, mt = w >> 1;
    int p = lane & 15, q = lane >> 4;
    int j = j0 + nt * 16 + p;
    const half8* pfv = (const half8*)pf;
    f32x4 acc = {0.f, 0.f, 0.f, 0.f};
#pragma unroll 3
    for (int s = 0; s < 18; s++) {
      int u = 4 * s + q, k = u >> 3, c0 = (u & 7) << 3;   // t = s*32+q*8 -> (k,c)
      int ki = (k * 86) >> 8, kj = k - ki * 3;            // k/3, k%3 for k<9
      half8 bfrag = *(const half8*)(x1b + ((size_t)(i + ki) * HP + (j + kj)) * CH + c0);
      acc = __builtin_amdgcn_mfma_f32_16x16x32_f16(pfv[(s * 2 + mt) * 64 + lane], bfrag, acc, 0, 0, 0);
    }
    int col = lane & 15, quad = lane >> 4;
    int px = nt * 16 + col;
#pragma unroll
    for (int r = 0; r < 4; r++) {
      int o = mt * 16 + quad * 4 + r;
      if (o < NOFF) offs[px * 20 + o] = acc[r] + pb[o];
    }
  }
  __syncthreads();

  // ---- Phase 2: coalesced gather + inline interp -> frag-ordered btile ----
  {
    int cg = tid & 7, px = tid >> 3;        // 32 px x 8 channel-chunks
    int c0 = cg * 8;
    int nt = px >> 4, pxl = px & 15, kgq = cg & 3, sh = cg >> 2;
    int j = j0 + px;
    _Float16* wslot = &btile[(((nt * 18) * 4 + kgq) * 16 + pxl) * 8];
#pragma unroll
    for (int k = 0; k < 9; k++) {
      float ox = offs[px * 20 + k];
      float oy = offs[px * 20 + k + 9];
      const int ki = k / 3, kj = k % 3;     // compile-time (fully unrolled)
      float pxr = (float)(i + ki) + ox;     // padded coords: p = p0 + p_n + off
      float pyr = (float)(j + kj) + oy;
      float fx = floorf(pxr), fy = floorf(pyr);
      float qltx = fminf(fmaxf(fx, 0.f), 129.f);
      float qlty = fminf(fmaxf(fy, 0.f), 129.f);
      float qrbx = fminf(fmaxf(fx + 1.f, 0.f), 129.f);
      float qrby = fminf(fmaxf(fy + 1.f, 0.f), 129.f);
      float pxc = fminf(fmaxf(pxr, 0.f), 129.f);
      float pyc = fminf(fmaxf(pyr, 0.f), 129.f);
      float glt = (1.f + qltx - pxc) * (1.f + qlty - pyc);
      float grb = (1.f - qrbx + pxc) * (1.f - qrby + pyc);
      float glb = (1.f + qltx - pxc) * (1.f - qrby + pyc);
      float grt = (1.f - qrbx + pxc) * (1.f + qlty - pyc);
      int ltx = (int)qltx, lty = (int)qlty;
      int rbx = (int)qrbx, rby = (int)qrby;
      const _Float16* rowl = x0b + (size_t)ltx * (HP * CH) + c0;
      const _Float16* rowr = x0b + (size_t)rbx * (HP * CH) + c0;
      half8 vlt = *(const half8*)(rowl + lty * CH);
      half8 vlb = *(const half8*)(rowl + rby * CH);
      half8 vrb = *(const half8*)(rowr + rby * CH);
      half8 vrt = *(const half8*)(rowr + lty * CH);
      half8 f = vlt * (_Float16)glt + vrb * (_Float16)grb +
                vlb * (_Float16)glb + vrt * (_Float16)grt;
      int s = k * 2 + sh;                   // t = k*64 + c0 + jj -> frag (s,kgq,pxl)
      *(half8*)(wslot + s * 512) = f;       // 512 halfs per s-step
    }
  }
  __syncthreads();

  // ---- Phase 3: main GEMM, D[oc][px], M=64, K=576 ----
  {
    int lane = tid & 63, w = tid >> 6;
    int nt = w & 1, mt0 = (w >> 1) * 2;
    f32x4 acc0 = {0.f, 0.f, 0.f, 0.f}, acc1 = {0.f, 0.f, 0.f, 0.f};
    const half8* wfv = (const half8*)wf;
    const half8* bt = (const half8*)&btile[nt * (18 * 512)];
#pragma unroll 6
    for (int s = 0; s < 18; s++) {
      half8 bfrag = bt[s * 64 + lane];
      acc0 = __builtin_amdgcn_mfma_f32_16x16x32_f16(wfv[(s * 4 + mt0) * 64 + lane], bfrag, acc0, 0, 0, 0);
      acc1 = __builtin_amdgcn_mfma_f32_16x16x32_f16(wfv[(s * 4 + mt0 + 1) * 64 + lane], bfrag, acc1, 0, 0, 0);
    }
    int col = lane & 15, quad = lane >> 4;
    int jo = j0 + nt * 16 + col;
#pragma unroll
    for (int r = 0; r < 4; r++) {
      int oc0 = mt0 * 16 + quad * 4 + r;
      int oc1 = (mt0 + 1) * 16 + quad * 4 + r;
      out[((b * OC + oc0) * HH + i) * WW + jo] = acc0[r];
      out[((b * OC + oc1) * HH + i) * WW + jo] = acc1[r];
    }
  }
}

// ---------------------------------------------------------------------------
extern "C" void kernel_launch(void* const* d_in, const int* in_sizes, int n_in,
                              void* d_out, int out_size, void* d_ws, size_t ws_size,
                              hipStream_t stream) {
  const float* x0 = (const float*)d_in[0];
  const float* x1 = (const float*)d_in[1];
  const float* pw = (const float*)d_in[2];
  const float* pb = (const float*)d_in[3];
  const float* cw = (const float*)d_in[4];
  float* out = (float*)d_out;

  _Float16* wfrag  = (_Float16*)((char*)d_ws + WF_OFF);
  _Float16* pwfrag = (_Float16*)((char*)d_ws + PF_OFF);
  _Float16* x0t    = (_Float16*)((char*)d_ws + X0T_OFF);
  _Float16* x1t    = (_Float16*)((char*)d_ws + X1T_OFF);

  prep_all<<<dim3(2280), dim3(256), 0, stream>>>(x0, x1, cw, pw, x0t, x1t, wfrag, pwfrag);
  deform_all<<<dim3(2048), dim3(256), 0, stream>>>(x0t, x1t, pwfrag, pb, wfrag, out);
}

// Round 10
// 114.351 us; speedup vs baseline: 1.1092x; 1.1092x over previous
//
#include <hip/hip_runtime.h>

// Problem: b=4, c=64, h=w=128, ks=3, N=9, offset ch=18, oc=64. Padded HP=130.
#define BATCH 4
#define CH    64
#define HH    128
#define WW    128
#define HW    (HH*WW)
#define HP    130
#define NOFF  18
#define OC    64

typedef _Float16 half8 __attribute__((ext_vector_type(8)));
typedef float f32x4 __attribute__((ext_vector_type(4)));

// ws layout (bytes):
//   wf  @ 0      : 36864 f16 (main A-frags)    pf @ 73728: 18432 f16
//   x0t @ 110592 : 4*130*130*64 f16 (padded NHWC, zero ring)
//   x1t @ 8763392: same                        total 17416192 B
#define WF_OFF  0
#define PF_OFF  73728
#define X0T_OFF 110592
#define X1T_OFF 8763392

// ---------------------------------------------------------------------------
// Kernel A: blocks 0..2047 transpose half-rows NCHW f32 -> padded NHWC f16;
// 2048..2063 zero ring rows; 2064..2279 A-fragments (k-major t = k*64+c).
// ---------------------------------------------------------------------------
__global__ __launch_bounds__(256) void prep_all(
    const float* __restrict__ x0, const float* __restrict__ x1,
    const float* __restrict__ cw, const float* __restrict__ pw,
    _Float16* __restrict__ x0t, _Float16* __restrict__ x1t,
    _Float16* __restrict__ wf, _Float16* __restrict__ pf) {
  int blk = blockIdx.x, tid = threadIdx.x;
  if (blk < 2048) {
    __shared__ float tile[64 * 66];
    int jh = blk & 1, i = (blk >> 1) & 127, b = (blk >> 8) & 3, which = blk >> 10;
    const float* src = which ? x1 : x0;
    _Float16* dst = which ? x1t : x0t;
#pragma unroll
    for (int it = 0; it < 4; it++) {
      int idx = it * 256 + tid;            // 1024 float4 = 64c x 64j
      int c = idx >> 4, j4 = (idx & 15) << 2;
      float4 v = *(const float4*)(src + (size_t)(b * CH + c) * HW + i * WW + jh * 64 + j4);
      *(float4*)&tile[c * 66 + j4] = v;
    }
    __syncthreads();
    int jl = tid >> 2, cq = (tid & 3) << 4;
    _Float16* dp = dst + ((size_t)(b * HP + i + 1) * HP + (jh * 64 + jl + 1)) * CH + cq;
#pragma unroll
    for (int h = 0; h < 2; h++) {
      half8 v;
#pragma unroll
      for (int cc = 0; cc < 8; cc++) v[cc] = (_Float16)tile[(cq + h * 8 + cc) * 66 + jl];
      *(half8*)(dp + h * 8) = v;
    }
    if (tid < 8) {                          // ring column jo=0 (jh0) / jo=129 (jh1)
      int jo = jh ? (HP - 1) : 0;
      _Float16* zp = dst + ((size_t)(b * HP + i + 1) * HP + jo) * CH + tid * 8;
      int4 z = {0, 0, 0, 0};
      *(int4*)zp = z;
    }
  } else if (blk < 2064) {
    int z = blk - 2048;
    int which = z >> 3, b = (z >> 1) & 3, top = z & 1;
    _Float16* dst = (which ? x1t : x0t) + ((size_t)(b * HP + top * (HP - 1)) * HP) * CH;
    int4 zz = {0, 0, 0, 0};
    for (int e = tid; e < 1040; e += 256) *(int4*)((char*)dst + e * 16) = zz;
  } else {
    int gid = (blk - 2064) * 256 + tid;     // 216*256 = 36864 + 18432
    if (gid < 36864) {
      int j = gid & 7, lane = (gid >> 3) & 63, mt = (gid >> 9) & 3, s = gid >> 11;
      int oc = mt * 16 + (lane & 15);
      int t = s * 32 + (lane >> 4) * 8 + j;
      int k = t >> 6, c = t & 63;
      wf[gid] = (_Float16)cw[(oc * CH + c) * 9 + k];
    } else {
      int g = gid - 36864;
      int j = g & 7, lane = (g >> 3) & 63, mt = (g >> 9) & 1, s = g >> 10;
      int o = mt * 16 + (lane & 15);
      int t = s * 32 + (lane >> 4) * 8 + j;
      int k = t >> 6, c = t & 63;
      pf[g] = (o < NOFF) ? (_Float16)pw[(o * CH + c) * 9 + k] : (_Float16)0.f;
    }
  }
}

// ---------------------------------------------------------------------------
// Kernel B: fully fused. Block = 32-px strip (b, i, j0), 256 thr, 4 blocks/CU
// (LDS 39424 B). Phases:
//  0. stage x1t patch (3 rows x 34 cols x 64ch = 13 KB) into btile-aliased
//     LDS, coalesced (13 full-width wave loads), padded stride 72 halfs.
//  1. offset GEMM: D[o][px], M=32 (18 used), K=576; B-frags via ds_read_b128
//     from the staged patch -> offs LDS. (R9 did scattered global loads here
//     -> 16-way line splits; that was the 51.7us regression.)
//  2. gather: tid = px*8+cg; interp weights inline from offs; 4 coalesced
//     corner loads; in-lane interp -> half8 IS one B-frag slot ->
//     ds_write_b128 into frag-ordered btile (overwrites staged patch).
//  3. main GEMM: D[oc][px], M=64, K=576, lane-indexed ds_read_b128 + MFMA.
// XCD band swizzle: each XCD owns 64 contiguous rows of one image.
// ---------------------------------------------------------------------------
__global__ __launch_bounds__(256, 4) void deform_all(
    const _Float16* __restrict__ x0t, const _Float16* __restrict__ x1t,
    const _Float16* __restrict__ pf, const float* __restrict__ pb,
    const _Float16* __restrict__ wf, float* __restrict__ out) {
  __shared__ __align__(16) _Float16 btile[2 * 18 * 64 * 8];   // 36864 B (aliased: phase0/1 x1s patch, phase2/3 frag tile)
  __shared__ float offs[32 * 20];                             // 2560 B

  int xcd = blockIdx.x & 7, local = blockIdx.x >> 3;
  int strip = xcd * 256 + local;            // 0..2047
  int jq2 = strip & 3, i = (strip >> 2) & 127, b = strip >> 9;
  int j0 = jq2 * 32;
  int tid = threadIdx.x;
  const _Float16* x0b = x0t + (size_t)b * HP * HP * CH;
  const _Float16* x1b = x1t + (size_t)b * HP * HP * CH;

  // ---- Phase 0: stage x1t patch rows i..i+2, cols j0..j0+33 (coalesced) ----
  {
#pragma unroll
    for (int it = 0; it < 4; it++) {
      int e = it * 256 + tid;               // 816 half8 chunks = 3*34*8
      if (e < 816) {
        int r = e / 272, rem = e - r * 272;
        int col = rem >> 3, cg8 = rem & 7;
        half8 v = *(const half8*)(x1b + ((size_t)(i + r) * HP + (j0 + col)) * CH + cg8 * 8);
        *(half8*)&btile[(r * 34 + col) * 72 + cg8 * 8] = v;
      }
    }
  }
  __syncthreads();

  // ---- Phase 1: offset GEMM (M=32 padded from 18, K=576), B from LDS ----
  {
    int lane = tid & 63, w = tid >> 6;
    int nt = w & 1, mt = w >> 1;
    int p = lane & 15, q = lane >> 4;
    const half8* pfv = (const half8*)pf;
    f32x4 acc = {0.f, 0.f, 0.f, 0.f};
#pragma unroll 3
    for (int s = 0; s < 18; s++) {
      int u = 4 * s + q, k = u >> 3, c0 = (u & 7) << 3;   // t = s*32+q*8 -> (k,c)
      int ki = (k * 86) >> 8, kj = k - ki * 3;            // k/3, k%3 for k<9
      half8 bfrag = *(const half8*)&btile[(ki * 34 + nt * 16 + p + kj) * 72 + c0];
      acc = __builtin_amdgcn_mfma_f32_16x16x32_f16(pfv[(s * 2 + mt) * 64 + lane], bfrag, acc, 0, 0, 0);
    }
    int col = lane & 15, quad = lane >> 4;
    int px = nt * 16 + col;
#pragma unroll
    for (int r = 0; r < 4; r++) {
      int o = mt * 16 + quad * 4 + r;
      if (o < NOFF) offs[px * 20 + o] = acc[r] + pb[o];
    }
  }
  __syncthreads();

  // ---- Phase 2: coalesced gather + inline interp -> frag-ordered btile ----
  {
    int cg = tid & 7, px = tid >> 3;        // 32 px x 8 channel-chunks
    int c0 = cg * 8;
    int nt = px >> 4, pxl = px & 15, kgq = cg & 3, sh = cg >> 2;
    int j = j0 + px;
    _Float16* wslot = &btile[(((nt * 18) * 4 + kgq) * 16 + pxl) * 8];
#pragma unroll
    for (int k = 0; k < 9; k++) {
      float ox = offs[px * 20 + k];
      float oy = offs[px * 20 + k + 9];
      const int ki = k / 3, kj = k % 3;     // compile-time (fully unrolled)
      float pxr = (float)(i + ki) + ox;     // padded coords: p = p0 + p_n + off
      float pyr = (float)(j + kj) + oy;
      float fx = floorf(pxr), fy = floorf(pyr);
      float qltx = fminf(fmaxf(fx, 0.f), 129.f);
      float qlty = fminf(fmaxf(fy, 0.f), 129.f);
      float qrbx = fminf(fmaxf(fx + 1.f, 0.f), 129.f);
      float qrby = fminf(fmaxf(fy + 1.f, 0.f), 129.f);
      float pxc = fminf(fmaxf(pxr, 0.f), 129.f);
      float pyc = fminf(fmaxf(pyr, 0.f), 129.f);
      float glt = (1.f + qltx - pxc) * (1.f + qlty - pyc);
      float grb = (1.f - qrbx + pxc) * (1.f - qrby + pyc);
      float glb = (1.f + qltx - pxc) * (1.f - qrby + pyc);
      float grt = (1.f - qrbx + pxc) * (1.f + qlty - pyc);
      int ltx = (int)qltx, lty = (int)qlty;
      int rbx = (int)qrbx, rby = (int)qrby;
      const _Float16* rowl = x0b + (size_t)ltx * (HP * CH) + c0;
      const _Float16* rowr = x0b + (size_t)rbx * (HP * CH) + c0;
      half8 vlt = *(const half8*)(rowl + lty * CH);
      half8 vlb = *(const half8*)(rowl + rby * CH);
      half8 vrb = *(const half8*)(rowr + rby * CH);
      half8 vrt = *(const half8*)(rowr + lty * CH);
      half8 f = vlt * (_Float16)glt + vrb * (_Float16)grb +
                vlb * (_Float16)glb + vrt * (_Float16)grt;
      int s = k * 2 + sh;                   // t = k*64 + c0 + jj -> frag (s,kgq,pxl)
      *(half8*)(wslot + s * 512) = f;       // 512 halfs per s-step
    }
  }
  __syncthreads();

  // ---- Phase 3: main GEMM, D[oc][px], M=64, K=576 ----
  {
    int lane = tid & 63, w = tid >> 6;
    int nt = w & 1, mt0 = (w >> 1) * 2;
    f32x4 acc0 = {0.f, 0.f, 0.f, 0.f}, acc1 = {0.f, 0.f, 0.f, 0.f};
    const half8* wfv = (const half8*)wf;
    const half8* bt = (const half8*)&btile[nt * (18 * 512)];
#pragma unroll 6
    for (int s = 0; s < 18; s++) {
      half8 bfrag = bt[s * 64 + lane];
      acc0 = __builtin_amdgcn_mfma_f32_16x16x32_f16(wfv[(s * 4 + mt0) * 64 + lane], bfrag, acc0, 0, 0, 0);
      acc1 = __builtin_amdgcn_mfma_f32_16x16x32_f16(wfv[(s * 4 + mt0 + 1) * 64 + lane], bfrag, acc1, 0, 0, 0);
    }
    int col = lane & 15, quad = lane >> 4;
    int jo = j0 + nt * 16 + col;
#pragma unroll
    for (int r = 0; r < 4; r++) {
      int oc0 = mt0 * 16 + quad * 4 + r;
      int oc1 = (mt0 + 1) * 16 + quad * 4 + r;
      out[((b * OC + oc0) * HH + i) * WW + jo] = acc0[r];
      out[((b * OC + oc1) * HH + i) * WW + jo] = acc1[r];
    }
  }
}

// ---------------------------------------------------------------------------
extern "C" void kernel_launch(void* const* d_in, const int* in_sizes, int n_in,
                              void* d_out, int out_size, void* d_ws, size_t ws_size,
                              hipStream_t stream) {
  const float* x0 = (const float*)d_in[0];
  const float* x1 = (const float*)d_in[1];
  const float* pw = (const float*)d_in[2];
  const float* pb = (const float*)d_in[3];
  const float* cw = (const float*)d_in[4];
  float* out = (float*)d_out;

  _Float16* wfrag  = (_Float16*)((char*)d_ws + WF_OFF);
  _Float16* pwfrag = (_Float16*)((char*)d_ws + PF_OFF);
  _Float16* x0t    = (_Float16*)((char*)d_ws + X0T_OFF);
  _Float16* x1t    = (_Float16*)((char*)d_ws + X1T_OFF);

  prep_all<<<dim3(2280), dim3(256), 0, stream>>>(x0, x1, cw, pw, x0t, x1t, wfrag, pwfrag);
  deform_all<<<dim3(2048), dim3(256), 0, stream>>>(x0t, x1t, pwfrag, pb, wfrag, out);
}